// Round 1
// baseline (2669.133 us; speedup 1.0000x reference)
//
#include <hip/hip_runtime.h>
#include <hip/hip_bf16.h>
#include <math.h>

// Problem constants (fixed by the harness inputs)
#define S_LEN   3072
#define DMODEL  1536
#define NHEAD   12
#define HDIM    128
#define ATT_SCALE 0.08838834764831843f   // 1/sqrt(128)

// partitioned index p -> original sequence index s
// p = ((fb*2+hb)*3+wb)*128 + wf*16 + wh*4 + ww ; s = (fi*8+hi)*12+wi
__device__ __forceinline__ int invperm(int p) {
  int blk = p >> 7;
  int w   = p & 127;
  int fb  = blk / 6;
  int rem = blk - fb * 6;
  int hb  = rem / 3;
  int wb  = rem - hb * 3;
  int wf  = w >> 4;
  int wh  = (w >> 2) & 3;
  int ww  = w & 3;
  int fi  = fb * 8 + wf;
  int hi  = hb * 4 + wh;
  int wi  = wb * 4 + ww;
  return (fi * 8 + hi) * 12 + wi;
}

// ---------------------------------------------------------------------------
// C[M,N] = A[M,K] @ B[K,N] + bias[N]   (fp32, 64x64 tile, 4x4 per thread)
// ---------------------------------------------------------------------------
__global__ __launch_bounds__(256) void gemm_bias(
    const float* __restrict__ A, const float* __restrict__ B,
    const float* __restrict__ bias, float* __restrict__ C,
    int M, int N, int K)
{
  __shared__ float As[16][65];   // [BK][BM+1]
  __shared__ float Bs[16][65];   // [BK][BN+1]
  const int tid = threadIdx.x;
  const int tx = tid & 15;       // col group: c = tx + 16j
  const int ty = tid >> 4;       // row group: r = ty + 16i
  const int row0 = blockIdx.y * 64;
  const int col0 = blockIdx.x * 64;

  float acc[4][4] = {};

  for (int k0 = 0; k0 < K; k0 += 16) {
    #pragma unroll
    for (int i = 0; i < 4; ++i) {
      int idx = tid + i * 256;          // 0..1023
      int r  = idx >> 4;                // 0..63
      int kk = idx & 15;
      As[kk][r] = A[(size_t)(row0 + r) * K + k0 + kk];
      int kb = idx >> 6;                // 0..15
      int c  = idx & 63;
      Bs[kb][c] = B[(size_t)(k0 + kb) * N + col0 + c];
    }
    __syncthreads();
    #pragma unroll
    for (int kk = 0; kk < 16; ++kk) {
      float a[4], b[4];
      #pragma unroll
      for (int i = 0; i < 4; ++i) a[i] = As[kk][ty + 16 * i];
      #pragma unroll
      for (int j = 0; j < 4; ++j) b[j] = Bs[kk][tx + 16 * j];
      #pragma unroll
      for (int i = 0; i < 4; ++i)
        #pragma unroll
        for (int j = 0; j < 4; ++j)
          acc[i][j] += a[i] * b[j];
    }
    __syncthreads();
  }

  #pragma unroll
  for (int i = 0; i < 4; ++i) {
    size_t r = row0 + ty + 16 * i;
    #pragma unroll
    for (int j = 0; j < 4; ++j) {
      int c = col0 + tx + 16 * j;
      C[r * N + c] = acc[i][j] + bias[c];
    }
  }
}

// ---------------------------------------------------------------------------
// In-place RMSNorm (eps=1e-5, weight g) + RoPE for one token row.
// grid.x = 3072 (token), 256 threads.
// ---------------------------------------------------------------------------
__global__ __launch_bounds__(256) void norm_rope(
    float* __restrict__ X, const float* __restrict__ g,
    const float* __restrict__ freqs)
{
  const int s = blockIdx.x;
  const int tid = threadIdx.x;
  float* row = X + (size_t)s * DMODEL;

  float ss = 0.f;
  #pragma unroll
  for (int i = 0; i < 6; ++i) {
    float v = row[tid + i * 256];
    ss += v * v;
  }
  #pragma unroll
  for (int off = 32; off > 0; off >>= 1) ss += __shfl_down(ss, off, 64);
  __shared__ float wsum[4];
  if ((tid & 63) == 0) wsum[tid >> 6] = ss;
  __syncthreads();
  float tot = wsum[0] + wsum[1] + wsum[2] + wsum[3];
  float rs = rsqrtf(tot * (1.0f / (float)DMODEL) + 1e-5f);

  // 768 rotation pairs, 3 per thread
  #pragma unroll
  for (int i = 0; i < 3; ++i) {
    int p = tid + i * 256;        // 0..767
    int n = p >> 6;               // head 0..11
    int d = p & 63;               // pair within head
    int base = n * HDIM + 2 * d;
    float e0 = row[base], e1 = row[base + 1];
    float c  = freqs[(size_t)s * 128 + 2 * d];
    float sn = freqs[(size_t)s * 128 + 2 * d + 1];
    float y0 = e0 * rs * g[base];
    float y1 = e1 * rs * g[base + 1];
    row[base]     = y0 * c - y1 * sn;
    row[base + 1] = y0 * sn + y1 * c;
  }
}

// ---------------------------------------------------------------------------
// Block-masked flash attention (fp32). grid = (48 query tiles, 12 heads).
// Query tile = 64 partitioned rows; keys iterated in 32-row chunks over the
// allowed contiguous ranges for the tile's temporal group. Q/K/V gathered
// from original-order buffers via invperm; O scattered back to original order.
// ---------------------------------------------------------------------------
__global__ __launch_bounds__(256) void attn_fwd(
    const float* __restrict__ Q, const float* __restrict__ K,
    const float* __restrict__ V, float* __restrict__ O)
{
  __shared__ float Qs[64][129];
  __shared__ float KVs[32][129];
  __shared__ float Ss[64][33];
  __shared__ float mrow[64], lrow[64], corr[64];
  __shared__ int   sqrow[64];

  const int qt  = blockIdx.x;      // 0..47
  const int h   = blockIdx.y;      // 0..11
  const int tid = threadIdx.x;
  const int tg  = qt / 12;         // temporal group 0..3

  if (tid < 64) {
    int p = qt * 64 + tid;
    sqrow[tid] = invperm(p);
    mrow[tid] = -3.0e38f;
    lrow[tid] = 0.0f;
  }
  __syncthreads();

  // stage Q: 4 threads per row, 8 float4 each
  {
    int r = tid >> 2, l = tid & 3;
    const float4* src = (const float4*)(Q + (size_t)sqrow[r] * DMODEL + h * HDIM);
    #pragma unroll
    for (int j = 0; j < 8; ++j) {
      int d4 = l + j * 4;
      float4 v = src[d4];
      Qs[r][d4 * 4 + 0] = v.x; Qs[r][d4 * 4 + 1] = v.y;
      Qs[r][d4 * 4 + 2] = v.z; Qs[r][d4 * 4 + 3] = v.w;
    }
  }

  const int tx = tid & 15;   // output dim group: d = tx + 16j
  const int ty = tid >> 4;   // output row group: r = ty + 16i
  float oacc[4][8];
  #pragma unroll
  for (int i = 0; i < 4; ++i)
    #pragma unroll
    for (int j = 0; j < 8; ++j) oacc[i][j] = 0.f;

  int r0lo = 0, r0hi = 0, r1lo = 0, r1hi = 0;
  if      (tg == 0) { r0hi = 1536; }
  else if (tg == 1) { r0hi = 2304; }
  else if (tg == 2) { r0hi = 3072; }
  else              { r0hi = 768; r1lo = 1536; r1hi = 3072; }

  for (int range = 0; range < 2; ++range) {
    const int lo = range ? r1lo : r0lo;
    const int hi = range ? r1hi : r0hi;
    for (int k0 = lo; k0 < hi; k0 += 32) {
      __syncthreads();   // previous PV done -> safe to overwrite KVs
      // stage K chunk: 8 threads per row, 4 float4 each
      {
        int c = tid >> 3, l = tid & 7;
        int sk = invperm(k0 + c);
        const float4* src = (const float4*)(K + (size_t)sk * DMODEL + h * HDIM);
        #pragma unroll
        for (int j = 0; j < 4; ++j) {
          int d4 = l + j * 8;
          float4 v = src[d4];
          KVs[c][d4 * 4 + 0] = v.x; KVs[c][d4 * 4 + 1] = v.y;
          KVs[c][d4 * 4 + 2] = v.z; KVs[c][d4 * 4 + 3] = v.w;
        }
      }
      __syncthreads();
      // scores: each thread 2 rows x 4 cols
      {
        int sr = tid & 31;
        int cg = tid >> 5;           // 0..7
        float a0[4] = {0.f, 0.f, 0.f, 0.f};
        float a1[4] = {0.f, 0.f, 0.f, 0.f};
        for (int d = 0; d < 128; ++d) {
          float qa = Qs[sr][d];
          float qb = Qs[sr + 32][d];
          #pragma unroll
          for (int j = 0; j < 4; ++j) {
            float kv = KVs[cg * 4 + j][d];
            a0[j] += qa * kv;
            a1[j] += qb * kv;
          }
        }
        #pragma unroll
        for (int j = 0; j < 4; ++j) {
          Ss[sr][cg * 4 + j]      = a0[j] * ATT_SCALE;
          Ss[sr + 32][cg * 4 + j] = a1[j] * ATT_SCALE;
        }
      }
      __syncthreads();
      // stage V chunk (overwrites KVs; K no longer needed)
      {
        int c = tid >> 3, l = tid & 7;
        int sk = invperm(k0 + c);
        const float4* src = (const float4*)(V + (size_t)sk * DMODEL + h * HDIM);
        #pragma unroll
        for (int j = 0; j < 4; ++j) {
          int d4 = l + j * 8;
          float4 v = src[d4];
          KVs[c][d4 * 4 + 0] = v.x; KVs[c][d4 * 4 + 1] = v.y;
          KVs[c][d4 * 4 + 2] = v.z; KVs[c][d4 * 4 + 3] = v.w;
        }
      }
      // online softmax per row (threads 0..63)
      if (tid < 64) {
        float m = mrow[tid];
        float mx = m;
        #pragma unroll
        for (int c = 0; c < 32; ++c) mx = fmaxf(mx, Ss[tid][c]);
        float cr = __expf(m - mx);
        float ls = 0.f;
        #pragma unroll
        for (int c = 0; c < 32; ++c) {
          float p = __expf(Ss[tid][c] - mx);
          Ss[tid][c] = p;
          ls += p;
        }
        lrow[tid] = lrow[tid] * cr + ls;
        mrow[tid] = mx;
        corr[tid] = cr;
      }
      __syncthreads();
      // PV accumulate
      {
        #pragma unroll
        for (int i = 0; i < 4; ++i) {
          float cr = corr[ty + 16 * i];
          #pragma unroll
          for (int j = 0; j < 8; ++j) oacc[i][j] *= cr;
        }
        for (int kk = 0; kk < 32; ++kk) {
          float p[4], v[8];
          #pragma unroll
          for (int i = 0; i < 4; ++i) p[i] = Ss[ty + 16 * i][kk];
          #pragma unroll
          for (int j = 0; j < 8; ++j) v[j] = KVs[kk][tx + 16 * j];
          #pragma unroll
          for (int i = 0; i < 4; ++i)
            #pragma unroll
            for (int j = 0; j < 8; ++j)
              oacc[i][j] += p[i] * v[j];
        }
      }
    }
  }

  // epilogue: normalize and scatter to original order
  #pragma unroll
  for (int i = 0; i < 4; ++i) {
    int r = ty + 16 * i;
    float inv = 1.0f / lrow[r];
    float* dst = O + (size_t)sqrow[r] * DMODEL + h * HDIM;
    #pragma unroll
    for (int j = 0; j < 8; ++j)
      dst[tx + 16 * j] = oacc[i][j] * inv;
  }
}

// ---------------------------------------------------------------------------
extern "C" void kernel_launch(void* const* d_in, const int* in_sizes, int n_in,
                              void* d_out, int out_size, void* d_ws, size_t ws_size,
                              hipStream_t stream)
{
  (void)in_sizes; (void)n_in; (void)out_size; (void)ws_size;
  const float* x     = (const float*)d_in[0];
  const float* freqs = (const float*)d_in[1];
  const float* Wq    = (const float*)d_in[2];
  const float* bq    = (const float*)d_in[3];
  const float* Wk    = (const float*)d_in[4];
  const float* bk    = (const float*)d_in[5];
  const float* Wv    = (const float*)d_in[6];
  const float* bv    = (const float*)d_in[7];
  const float* Wo    = (const float*)d_in[8];
  const float* bo    = (const float*)d_in[9];
  const float* gq    = (const float*)d_in[10];
  const float* gk    = (const float*)d_in[11];
  float* out = (float*)d_out;

  const size_t SZ = (size_t)S_LEN * DMODEL;
  float* Qb = (float*)d_ws;
  float* Kb = Qb + SZ;
  float* Vb = Kb + SZ;
  float* AO = Vb + SZ;

  dim3 gg(DMODEL / 64, S_LEN / 64), bb(256);
  hipLaunchKernelGGL(gemm_bias, gg, bb, 0, stream, x, Wq, bq, Qb, S_LEN, DMODEL, DMODEL);
  hipLaunchKernelGGL(gemm_bias, gg, bb, 0, stream, x, Wk, bk, Kb, S_LEN, DMODEL, DMODEL);
  hipLaunchKernelGGL(gemm_bias, gg, bb, 0, stream, x, Wv, bv, Vb, S_LEN, DMODEL, DMODEL);

  hipLaunchKernelGGL(norm_rope, dim3(S_LEN), bb, 0, stream, Qb, gq, freqs);
  hipLaunchKernelGGL(norm_rope, dim3(S_LEN), bb, 0, stream, Kb, gk, freqs);

  hipLaunchKernelGGL(attn_fwd, dim3(48, NHEAD), bb, 0, stream, Qb, Kb, Vb, AO);

  hipLaunchKernelGGL(gemm_bias, gg, bb, 0, stream, AO, Wo, bo, out, S_LEN, DMODEL, DMODEL);
}

// Round 3
// 354.693 us; speedup vs baseline: 7.5252x; 7.5252x over previous
//
#include <hip/hip_runtime.h>
#include <hip/hip_bf16.h>
#include <math.h>

#define S_LEN 3072
#define DMODEL 1536
#define NQKV 4608
#define NHEAD 12
#define HDIM 128

typedef __attribute__((ext_vector_type(8))) short bf16x8;
typedef __attribute__((ext_vector_type(4))) float f32x4;

__device__ __forceinline__ void gload_lds16(const void* g, void* lds) {
  __builtin_amdgcn_global_load_lds(
      (const __attribute__((address_space(1))) unsigned int*)g,
      (__attribute__((address_space(3))) unsigned int*)lds, 16, 0, 0);
}

// partitioned index p -> original sequence index s
__device__ __forceinline__ int invperm(int p) {
  int blk = p >> 7;
  int w   = p & 127;
  int fb  = blk / 6;
  int rem = blk - fb * 6;
  int hb  = rem / 3;
  int wb  = rem - hb * 3;
  int fi  = fb * 8 + (w >> 4);
  int hi  = hb * 4 + ((w >> 2) & 3);
  int wi  = wb * 4 + (w & 3);
  return (fi * 8 + hi) * 12 + wi;
}

// original sequence index s -> partitioned index p
__device__ __forceinline__ int fwdperm(int s) {
  int fi = s / 96;
  int rem = s - fi * 96;
  int hi = rem / 12;
  int wi = rem - hi * 12;
  int fb = fi >> 3, wf = fi & 7;
  int hb = hi >> 2, wh = hi & 3;
  int wb = wi >> 2, ww = wi & 3;
  return ((fb * 2 + hb) * 3 + wb) * 128 + wf * 16 + wh * 4 + ww;
}

__device__ __forceinline__ void store_out(float* p, float v) { *p = v; }
__device__ __forceinline__ void store_out(__hip_bfloat16* p, float v) { *p = __float2bfloat16(v); }

// ---------------------------------------------------------------------------
// fp32 -> bf16 convert (vectorized, n4 = n/4)
// ---------------------------------------------------------------------------
__global__ __launch_bounds__(256) void convert_f32_bf16(
    const float* __restrict__ in, __hip_bfloat16* __restrict__ out, int n4)
{
  int i = blockIdx.x * 256 + threadIdx.x;
  if (i >= n4) return;
  float4 v = ((const float4*)in)[i];
  __hip_bfloat16 b[4] = {__float2bfloat16(v.x), __float2bfloat16(v.y),
                         __float2bfloat16(v.z), __float2bfloat16(v.w)};
  ((ushort4*)out)[i] = *(ushort4*)b;
}

// ---------------------------------------------------------------------------
// W [1536][1536] fp32 -> Wt [1536][1536] bf16 transposed (64x64 LDS tiles)
// ---------------------------------------------------------------------------
__global__ __launch_bounds__(256) void transpose_convert(
    const float* __restrict__ W, __hip_bfloat16* __restrict__ Wt)
{
  __shared__ __hip_bfloat16 Ls[64][67];
  const int r0 = blockIdx.y * 64, c0 = blockIdx.x * 64, t = threadIdx.x;
  {
    int rr = t >> 2, cb = (t & 3) * 16;
    const float4* src = (const float4*)(W + (size_t)(r0 + rr) * DMODEL + c0 + cb);
    #pragma unroll
    for (int i = 0; i < 4; ++i) {
      float4 v = src[i];
      Ls[rr][cb + i * 4 + 0] = __float2bfloat16(v.x);
      Ls[rr][cb + i * 4 + 1] = __float2bfloat16(v.y);
      Ls[rr][cb + i * 4 + 2] = __float2bfloat16(v.z);
      Ls[rr][cb + i * 4 + 3] = __float2bfloat16(v.w);
    }
  }
  __syncthreads();
  {
    int cc = t >> 2, rb = (t & 3) * 16;
    unsigned short tmp[16];
    #pragma unroll
    for (int i = 0; i < 16; ++i) tmp[i] = *(unsigned short*)&Ls[rb + i][cc];
    uint4* dst = (uint4*)(Wt + (size_t)(c0 + cc) * DMODEL + r0 + rb);
    dst[0] = ((uint4*)tmp)[0];
    dst[1] = ((uint4*)tmp)[1];
  }
}

__global__ void concat3(const float* __restrict__ a, const float* __restrict__ b,
                        const float* __restrict__ c, float* __restrict__ o)
{
  int i = blockIdx.x * 256 + threadIdx.x;
  if (i < 1536) o[i] = a[i];
  else if (i < 3072) o[i] = b[i - 1536];
  else if (i < 4608) o[i] = c[i - 3072];
}

// ---------------------------------------------------------------------------
// bf16 MFMA GEMM (m97 structure): C[M,N] = A[M,K] @ Bt[N,K]^T + bias
// 128x128 tile, BK=32, 4 waves (2x2), global_load_lds width-16 staging.
// ---------------------------------------------------------------------------
template <typename OutT>
__global__ __launch_bounds__(256) void gemm_bt(
    const __hip_bfloat16* __restrict__ A, const __hip_bfloat16* __restrict__ Bt,
    const float* __restrict__ bias, OutT* __restrict__ C, int M, int N, int K)
{
  __shared__ __hip_bfloat16 As[128 * 32];
  __shared__ __hip_bfloat16 Bs[128 * 32];
  const int tid = threadIdx.x, lane = tid & 63, wid = tid >> 6;
  const int l15 = lane & 15, l4 = lane >> 4;
  const int row0 = blockIdx.y * 128, col0 = blockIdx.x * 128;
  const int wr = (wid >> 1) * 64, wc = (wid & 1) * 64;

  f32x4 acc[4][4] = {};
  const char* Ab = (const char*)A;
  const char* Bb = (const char*)Bt;

  for (int k0 = 0; k0 < K; k0 += 32) {
    __syncthreads();
    #pragma unroll
    for (int i = 0; i < 2; ++i) {
      int slot = i * 256 + tid;
      int r = slot >> 2;
      int b = (slot & 3) * 16;
      gload_lds16(Ab + ((size_t)(row0 + r) * K + k0) * 2 + b,
                  (char*)As + ((size_t)i * 256 + wid * 64) * 16);
      gload_lds16(Bb + ((size_t)(col0 + r) * K + k0) * 2 + b,
                  (char*)Bs + ((size_t)i * 256 + wid * 64) * 16);
    }
    __syncthreads();
    bf16x8 a[4], b[4];
    #pragma unroll
    for (int m = 0; m < 4; ++m)
      a[m] = *(const bf16x8*)&As[(wr + m * 16 + l15) * 32 + l4 * 8];
    #pragma unroll
    for (int n = 0; n < 4; ++n)
      b[n] = *(const bf16x8*)&Bs[(wc + n * 16 + l15) * 32 + l4 * 8];
    #pragma unroll
    for (int m = 0; m < 4; ++m)
      #pragma unroll
      for (int n = 0; n < 4; ++n)
        acc[m][n] = __builtin_amdgcn_mfma_f32_16x16x32_bf16(a[m], b[n], acc[m][n], 0, 0, 0);
  }

  #pragma unroll
  for (int m = 0; m < 4; ++m) {
    #pragma unroll
    for (int r = 0; r < 4; ++r) {
      size_t row = row0 + wr + m * 16 + l4 * 4 + r;
      #pragma unroll
      for (int n = 0; n < 4; ++n) {
        int col = col0 + wc + n * 16 + l15;
        store_out(&C[row * N + col], acc[m][n][r] + bias[col]);
      }
    }
  }
}

// ---------------------------------------------------------------------------
// RMSNorm + RoPE, reading one QKV column section, writing permuted head-blocked
// bf16: Out[h][p][d].  grid = 3072 (token s), 256 threads.
// ---------------------------------------------------------------------------
__global__ __launch_bounds__(256) void norm_rope_perm(
    const __hip_bfloat16* __restrict__ X, int co,
    const float* __restrict__ g, const float* __restrict__ freqs,
    __hip_bfloat16* __restrict__ Out)
{
  const int s = blockIdx.x, tid = threadIdx.x;
  const unsigned int* row = (const unsigned int*)(X + (size_t)s * NQKV + co);
  float e0[3], e1[3];
  float ss = 0.f;
  #pragma unroll
  for (int i = 0; i < 3; ++i) {
    unsigned int u = row[tid + i * 256];
    float a = __uint_as_float(u << 16);
    float b = __uint_as_float(u & 0xffff0000u);
    e0[i] = a; e1[i] = b;
    ss += a * a + b * b;
  }
  #pragma unroll
  for (int off = 32; off > 0; off >>= 1) ss += __shfl_down(ss, off, 64);
  __shared__ float wsum[4];
  if ((tid & 63) == 0) wsum[tid >> 6] = ss;
  __syncthreads();
  float rs = rsqrtf((wsum[0] + wsum[1] + wsum[2] + wsum[3]) * (1.f / DMODEL) + 1e-5f);
  const int p = fwdperm(s);
  #pragma unroll
  for (int i = 0; i < 3; ++i) {
    int pi = tid + i * 256;             // pair index 0..767
    int n = pi >> 6, d2 = pi & 63;
    float c  = freqs[(size_t)s * 128 + 2 * d2];
    float sn = freqs[(size_t)s * 128 + 2 * d2 + 1];
    float y0 = e0[i] * rs * g[2 * pi];
    float y1 = e1[i] * rs * g[2 * pi + 1];
    float o0 = y0 * c - y1 * sn;
    float o1 = y0 * sn + y1 * c;
    __hip_bfloat16 b0 = __float2bfloat16(o0), b1 = __float2bfloat16(o1);
    unsigned int u = ((unsigned int)(*(unsigned short*)&b1) << 16) | (*(unsigned short*)&b0);
    ((unsigned int*)Out)[(((size_t)n * S_LEN + p) * HDIM + 2 * d2) >> 1] = u;
  }
}

// ---------------------------------------------------------------------------
// V section of QKV -> Vt[h][d][p] bf16 (transposed + permuted), 64p x 128d tiles
// ---------------------------------------------------------------------------
__global__ __launch_bounds__(256) void v_transpose(
    const __hip_bfloat16* __restrict__ Vsec, __hip_bfloat16* __restrict__ Vt)
{
  __shared__ __hip_bfloat16 Ls[64][136];
  const int p0 = blockIdx.x * 64, h = blockIdx.y, t = threadIdx.x;
  {
    int pl = t & 63, dg = t >> 6;
    int sidx = invperm(p0 + pl);
    const uint4* src = (const uint4*)(Vsec + (size_t)sidx * NQKV + h * HDIM + dg * 32);
    #pragma unroll
    for (int i = 0; i < 4; ++i) {
      uint4 v = src[i];
      *(uint4*)&Ls[pl][dg * 32 + i * 8] = v;
    }
  }
  __syncthreads();
  {
    int d = t >> 1, ph = t & 1;
    unsigned short tmp[32];
    #pragma unroll
    for (int i = 0; i < 32; ++i) tmp[i] = *(unsigned short*)&Ls[ph * 32 + i][d];
    uint4* dst = (uint4*)(Vt + ((size_t)h * HDIM + d) * S_LEN + p0 + ph * 32);
    #pragma unroll
    for (int i = 0; i < 4; ++i) dst[i] = ((uint4*)tmp)[i];
  }
}

// ---------------------------------------------------------------------------
// MFMA flash attention.  grid=(48 qtile, 12 head), 4 waves x 16 q-rows.
// KC=64 key chunks over exact allowed ranges.  Ks/Vs XOR-swizzled LDS,
// in-register online softmax, P through per-wave padded LDS tile.
// ---------------------------------------------------------------------------
__global__ __launch_bounds__(256) void attn_mfma(
    const __hip_bfloat16* __restrict__ Qp, const __hip_bfloat16* __restrict__ Kp,
    const __hip_bfloat16* __restrict__ Vt, __hip_bfloat16* __restrict__ AO)
{
  __shared__ __hip_bfloat16 Ks[64 * 128];          // [key][d], swizzled
  __shared__ __hip_bfloat16 Vs[128 * 64];          // [d][key], swizzled
  __shared__ __align__(16) __hip_bfloat16 Pl[4][16][72];  // 64 keys + 8 pad

  const int qt = blockIdx.x, h = blockIdx.y;
  const int tid = threadIdx.x, lane = tid & 63, wid = tid >> 6;
  const int l15 = lane & 15, l4 = lane >> 4;
  const float SC2 = 0.08838834764831843f * 1.4426950408889634f;

  const char* Kh = (const char*)(Kp + (size_t)h * S_LEN * HDIM);
  const char* Vh = (const char*)(Vt + (size_t)h * HDIM * S_LEN);

  // hoist Q fragments (A-operand) to registers
  bf16x8 aq[4];
  {
    const __hip_bfloat16* qr =
        Qp + (size_t)h * S_LEN * HDIM + (size_t)(qt * 64 + wid * 16 + l15) * HDIM + l4 * 8;
    #pragma unroll
    for (int dc = 0; dc < 4; ++dc) aq[dc] = *(const bf16x8*)(qr + dc * 32);
  }

  f32x4 oacc[8] = {};
  float m2[4] = {-1e30f, -1e30f, -1e30f, -1e30f};
  float lsum[4] = {};

  int lo0 = 0, hi0, lo1 = 0, hi1 = 0;
  const int tg = qt / 12;
  if (tg == 0) hi0 = 1536;
  else if (tg == 1) hi0 = 2304;
  else if (tg == 2) hi0 = 3072;
  else { hi0 = 768; lo1 = 1536; hi1 = 3072; }

  for (int range = 0; range < 2; ++range) {
    const int lo = range ? lo1 : lo0;
    const int hi = range ? hi1 : hi0;
    for (int k0 = lo; k0 < hi; k0 += 64) {
      __syncthreads();
      // stage K (64x128) and Vt (128x64) chunks, pre-swizzled source
      #pragma unroll
      for (int i = 0; i < 4; ++i) {
        int slot = i * 256 + tid;
        int krow = slot >> 4;
        int kb = (slot & 15) * 16;
        int ksb = kb ^ ((krow & 7) << 4);
        gload_lds16(Kh + ((size_t)(k0 + krow) * HDIM) * 2 + ksb,
                    (char*)Ks + ((size_t)i * 256 + wid * 64) * 16);
        int vrow = slot >> 3;
        int vb = (slot & 7) * 16;
        int vsb = vb ^ ((vrow & 7) << 4);
        gload_lds16(Vh + ((size_t)vrow * S_LEN + k0) * 2 + vsb,
                    (char*)Vs + ((size_t)i * 256 + wid * 64) * 16);
      }
      __syncthreads();
      // QK^T: S[16q][64k] per wave
      f32x4 sfr[4] = {};
      #pragma unroll
      for (int ct = 0; ct < 4; ++ct) {
        int key = ct * 16 + l15;
        #pragma unroll
        for (int dc = 0; dc < 4; ++dc) {
          int b = (dc * 64 + l4 * 16) ^ ((key & 7) << 4);
          bf16x8 bk = *(const bf16x8*)((const char*)Ks + key * 256 + b);
          sfr[ct] = __builtin_amdgcn_mfma_f32_16x16x32_bf16(aq[dc], bk, sfr[ct], 0, 0, 0);
        }
      }
      // online softmax (rows live at (l4*4+r); reduce over low-4 lane bits)
      float corr[4];
      #pragma unroll
      for (int r = 0; r < 4; ++r) {
        float mx = fmaxf(fmaxf(sfr[0][r], sfr[1][r]), fmaxf(sfr[2][r], sfr[3][r])) * SC2;
        #pragma unroll
        for (int o = 1; o < 16; o <<= 1) mx = fmaxf(mx, __shfl_xor(mx, o, 64));
        float mn = fmaxf(m2[r], mx);
        corr[r] = exp2f(m2[r] - mn);
        m2[r] = mn;
      }
      float pr[4][4];
      float rsum[4] = {};
      #pragma unroll
      for (int ct = 0; ct < 4; ++ct)
        #pragma unroll
        for (int r = 0; r < 4; ++r) {
          float p = exp2f(sfr[ct][r] * SC2 - m2[r]);
          pr[ct][r] = p;
          rsum[r] += p;
        }
      #pragma unroll
      for (int r = 0; r < 4; ++r) {
        float t = rsum[r];
        #pragma unroll
        for (int o = 1; o < 16; o <<= 1) t += __shfl_xor(t, o, 64);
        lsum[r] = lsum[r] * corr[r] + t;
      }
      #pragma unroll
      for (int n = 0; n < 8; ++n)
        #pragma unroll
        for (int r = 0; r < 4; ++r) oacc[n][r] *= corr[r];
      // P -> per-wave LDS tile (A-operand relayout)
      #pragma unroll
      for (int ct = 0; ct < 4; ++ct)
        #pragma unroll
        for (int r = 0; r < 4; ++r)
          Pl[wid][l4 * 4 + r][ct * 16 + l15] = __float2bfloat16(pr[ct][r]);
      asm volatile("s_waitcnt lgkmcnt(0)" ::: "memory");
      // PV
      #pragma unroll
      for (int ks = 0; ks < 2; ++ks) {
        bf16x8 pa = *(const bf16x8*)&Pl[wid][l15][ks * 32 + l4 * 8];
        #pragma unroll
        for (int n = 0; n < 8; ++n) {
          int d = n * 16 + l15;
          int b = (ks * 64 + l4 * 16) ^ ((d & 7) << 4);
          bf16x8 bv = *(const bf16x8*)((const char*)Vs + d * 128 + b);
          oacc[n] = __builtin_amdgcn_mfma_f32_16x16x32_bf16(pa, bv, oacc[n], 0, 0, 0);
        }
      }
    }
  }

  // epilogue: normalize, scatter back to original token order
  #pragma unroll
  for (int r = 0; r < 4; ++r) {
    int qglob = qt * 64 + wid * 16 + l4 * 4 + r;
    int sorig = invperm(qglob);
    float inv = 1.0f / lsum[r];
    __hip_bfloat16* dst = AO + (size_t)sorig * DMODEL + h * HDIM;
    #pragma unroll
    for (int n = 0; n < 8; ++n)
      dst[n * 16 + l15] = __float2bfloat16(oacc[n][r] * inv);
  }
}

// ---------------------------------------------------------------------------
extern "C" void kernel_launch(void* const* d_in, const int* in_sizes, int n_in,
                              void* d_out, int out_size, void* d_ws, size_t ws_size,
                              hipStream_t stream)
{
  (void)in_sizes; (void)n_in; (void)out_size; (void)ws_size;
  const float* x     = (const float*)d_in[0];
  const float* freqs = (const float*)d_in[1];
  const float* Wq    = (const float*)d_in[2];
  const float* bq    = (const float*)d_in[3];
  const float* Wk    = (const float*)d_in[4];
  const float* bk    = (const float*)d_in[5];
  const float* Wv    = (const float*)d_in[6];
  const float* bv    = (const float*)d_in[7];
  const float* Wo    = (const float*)d_in[8];
  const float* bo    = (const float*)d_in[9];
  const float* gq    = (const float*)d_in[10];
  const float* gk    = (const float*)d_in[11];
  float* out = (float*)d_out;

  char* w = (char*)d_ws;
  __hip_bfloat16* xbf    = (__hip_bfloat16*)(w);               // 9,437,184 B
  __hip_bfloat16* Wtqkv  = (__hip_bfloat16*)(w + 9437184);     // 14,155,776
  __hip_bfloat16* Wot    = (__hip_bfloat16*)(w + 23592960);    // 4,718,592
  __hip_bfloat16* QKVbf  = (__hip_bfloat16*)(w + 28311552);    // 28,311,552
  __hip_bfloat16* Qp     = (__hip_bfloat16*)(w + 56623104);    // 9,437,184
  __hip_bfloat16* Kp     = (__hip_bfloat16*)(w + 66060288);    // 9,437,184
  __hip_bfloat16* Vtb    = (__hip_bfloat16*)(w + 75497472);    // 9,437,184
  __hip_bfloat16* AO     = (__hip_bfloat16*)(w + 84934656);    // 9,437,184
  float*          bqkv   = (float*)(w + 94371840);             // 18,432

  // prep: converts / transposes / bias concat
  hipLaunchKernelGGL(convert_f32_bf16, dim3(4608), dim3(256), 0, stream,
                     x, xbf, (S_LEN * DMODEL) / 4);
  dim3 tg(24, 24);
  hipLaunchKernelGGL(transpose_convert, tg, dim3(256), 0, stream, Wq, Wtqkv);
  hipLaunchKernelGGL(transpose_convert, tg, dim3(256), 0, stream, Wk, Wtqkv + (size_t)1536 * 1536);
  hipLaunchKernelGGL(transpose_convert, tg, dim3(256), 0, stream, Wv, Wtqkv + (size_t)3072 * 1536);
  hipLaunchKernelGGL(transpose_convert, tg, dim3(256), 0, stream, Wo, Wot);
  hipLaunchKernelGGL(concat3, dim3(18), dim3(256), 0, stream, bq, bk, bv, bqkv);

  // fused QKV GEMM: [3072,1536] @ [1536,4608] -> bf16
  hipLaunchKernelGGL((gemm_bt<__hip_bfloat16>), dim3(NQKV / 128, S_LEN / 128), dim3(256), 0,
                     stream, xbf, Wtqkv, bqkv, QKVbf, S_LEN, NQKV, DMODEL);

  // norm+rope -> permuted head-blocked Q/K ; V -> transposed+permuted
  hipLaunchKernelGGL(norm_rope_perm, dim3(S_LEN), dim3(256), 0, stream, QKVbf, 0, gq, freqs, Qp);
  hipLaunchKernelGGL(norm_rope_perm, dim3(S_LEN), dim3(256), 0, stream, QKVbf, 1536, gk, freqs, Kp);
  hipLaunchKernelGGL(v_transpose, dim3(48, 12), dim3(256), 0, stream, QKVbf + 3072, Vtb);

  // attention
  hipLaunchKernelGGL(attn_mfma, dim3(48, NHEAD), dim3(256), 0, stream, Qp, Kp, Vtb, AO);

  // output projection
  hipLaunchKernelGGL((gemm_bt<float>), dim3(DMODEL / 128, S_LEN / 128), dim3(256), 0,
                     stream, AO, Wot, bo, out, S_LEN, DMODEL, DMODEL);
}

// Round 4
// 346.420 us; speedup vs baseline: 7.7049x; 1.0239x over previous
//
#include <hip/hip_runtime.h>
#include <hip/hip_bf16.h>
#include <math.h>

#define S_LEN 3072
#define DMODEL 1536
#define NQKV 4608
#define NHEAD 12
#define HDIM 128

typedef __attribute__((ext_vector_type(8))) short bf16x8;
typedef __attribute__((ext_vector_type(4))) float f32x4;

__device__ __forceinline__ void gload_lds16(const void* g, void* lds) {
  __builtin_amdgcn_global_load_lds(
      (const __attribute__((address_space(1))) unsigned int*)g,
      (__attribute__((address_space(3))) unsigned int*)lds, 16, 0, 0);
}

// partitioned index p -> original sequence index s
__device__ __forceinline__ int invperm(int p) {
  int blk = p >> 7;
  int w   = p & 127;
  int fb  = blk / 6;
  int rem = blk - fb * 6;
  int hb  = rem / 3;
  int wb  = rem - hb * 3;
  int fi  = fb * 8 + (w >> 4);
  int hi  = hb * 4 + ((w >> 2) & 3);
  int wi  = wb * 4 + (w & 3);
  return (fi * 8 + hi) * 12 + wi;
}

// original sequence index s -> partitioned index p
__device__ __forceinline__ int fwdperm(int s) {
  int fi = s / 96;
  int rem = s - fi * 96;
  int hi = rem / 12;
  int wi = rem - hi * 12;
  int fb = fi >> 3, wf = fi & 7;
  int hb = hi >> 2, wh = hi & 3;
  int wb = wi >> 2, ww = wi & 3;
  return ((fb * 2 + hb) * 3 + wb) * 128 + wf * 16 + wh * 4 + ww;
}

__device__ __forceinline__ void store_out(float* p, float v) { *p = v; }
__device__ __forceinline__ void store_out(__hip_bfloat16* p, float v) { *p = __float2bfloat16(v); }

// ---------------------------------------------------------------------------
__global__ __launch_bounds__(256) void convert_f32_bf16(
    const float* __restrict__ in, __hip_bfloat16* __restrict__ out, int n4)
{
  int i = blockIdx.x * 256 + threadIdx.x;
  if (i >= n4) return;
  float4 v = ((const float4*)in)[i];
  __hip_bfloat16 b[4] = {__float2bfloat16(v.x), __float2bfloat16(v.y),
                         __float2bfloat16(v.z), __float2bfloat16(v.w)};
  ((ushort4*)out)[i] = *(ushort4*)b;
}

// ---------------------------------------------------------------------------
__global__ __launch_bounds__(256) void transpose_convert(
    const float* __restrict__ W, __hip_bfloat16* __restrict__ Wt)
{
  __shared__ __hip_bfloat16 Ls[64][67];
  const int r0 = blockIdx.y * 64, c0 = blockIdx.x * 64, t = threadIdx.x;
  {
    int rr = t >> 2, cb = (t & 3) * 16;
    const float4* src = (const float4*)(W + (size_t)(r0 + rr) * DMODEL + c0 + cb);
    #pragma unroll
    for (int i = 0; i < 4; ++i) {
      float4 v = src[i];
      Ls[rr][cb + i * 4 + 0] = __float2bfloat16(v.x);
      Ls[rr][cb + i * 4 + 1] = __float2bfloat16(v.y);
      Ls[rr][cb + i * 4 + 2] = __float2bfloat16(v.z);
      Ls[rr][cb + i * 4 + 3] = __float2bfloat16(v.w);
    }
  }
  __syncthreads();
  {
    int cc = t >> 2, rb = (t & 3) * 16;
    unsigned short tmp[16];
    #pragma unroll
    for (int i = 0; i < 16; ++i) tmp[i] = *(unsigned short*)&Ls[rb + i][cc];
    uint4* dst = (uint4*)(Wt + (size_t)(c0 + cc) * DMODEL + r0 + rb);
    dst[0] = ((uint4*)tmp)[0];
    dst[1] = ((uint4*)tmp)[1];
  }
}

__global__ void concat3(const float* __restrict__ a, const float* __restrict__ b,
                        const float* __restrict__ c, float* __restrict__ o)
{
  int i = blockIdx.x * 256 + threadIdx.x;
  if (i < 1536) o[i] = a[i];
  else if (i < 3072) o[i] = b[i - 1536];
  else if (i < 4608) o[i] = c[i - 3072];
}

// ---------------------------------------------------------------------------
// bf16 MFMA GEMM, 128x128 tile, BK=32, double-buffered single-barrier loop:
// issue STAGE(next) early, compute cur, drain+barrier late (latency hidden).
// ---------------------------------------------------------------------------
template <typename OutT>
__global__ __launch_bounds__(256) void gemm_bt(
    const __hip_bfloat16* __restrict__ A, const __hip_bfloat16* __restrict__ Bt,
    const float* __restrict__ bias, OutT* __restrict__ C, int M, int N, int K)
{
  __shared__ __hip_bfloat16 As[2][128 * 32];
  __shared__ __hip_bfloat16 Bs[2][128 * 32];
  const int tid = threadIdx.x, lane = tid & 63, wid = tid >> 6;
  const int l15 = lane & 15, l4 = lane >> 4;
  const int row0 = blockIdx.y * 128, col0 = blockIdx.x * 128;
  const int wr = (wid >> 1) * 64, wc = (wid & 1) * 64;

  f32x4 acc[4][4] = {};
  const char* Ab = (const char*)A;
  const char* Bb = (const char*)Bt;

  auto STAGE = [&](int buf, int k0) {
    #pragma unroll
    for (int i = 0; i < 2; ++i) {
      int slot = i * 256 + tid;
      int r = slot >> 2;
      int b = (slot & 3) * 16;
      gload_lds16(Ab + ((size_t)(row0 + r) * K + k0) * 2 + b,
                  (char*)As[buf] + ((size_t)i * 256 + wid * 64) * 16);
      gload_lds16(Bb + ((size_t)(col0 + r) * K + k0) * 2 + b,
                  (char*)Bs[buf] + ((size_t)i * 256 + wid * 64) * 16);
    }
  };

  STAGE(0, 0);
  __syncthreads();
  int cur = 0;
  for (int k0 = 0; k0 < K; k0 += 32) {
    if (k0 + 32 < K) STAGE(cur ^ 1, k0 + 32);
    bf16x8 a[4], b[4];
    #pragma unroll
    for (int m = 0; m < 4; ++m)
      a[m] = *(const bf16x8*)&As[cur][(wr + m * 16 + l15) * 32 + l4 * 8];
    #pragma unroll
    for (int n = 0; n < 4; ++n)
      b[n] = *(const bf16x8*)&Bs[cur][(wc + n * 16 + l15) * 32 + l4 * 8];
    #pragma unroll
    for (int m = 0; m < 4; ++m)
      #pragma unroll
      for (int n = 0; n < 4; ++n)
        acc[m][n] = __builtin_amdgcn_mfma_f32_16x16x32_bf16(a[m], b[n], acc[m][n], 0, 0, 0);
    __syncthreads();
    cur ^= 1;
  }

  #pragma unroll
  for (int m = 0; m < 4; ++m) {
    #pragma unroll
    for (int r = 0; r < 4; ++r) {
      size_t row = row0 + wr + m * 16 + l4 * 4 + r;
      #pragma unroll
      for (int n = 0; n < 4; ++n) {
        int col = col0 + wc + n * 16 + l15;
        store_out(&C[row * N + col], acc[m][n][r] + bias[col]);
      }
    }
  }
}

// ---------------------------------------------------------------------------
__global__ __launch_bounds__(256) void norm_rope_perm(
    const __hip_bfloat16* __restrict__ X, int co,
    const float* __restrict__ g, const float* __restrict__ freqs,
    __hip_bfloat16* __restrict__ Out)
{
  const int s = blockIdx.x, tid = threadIdx.x;
  const unsigned int* row = (const unsigned int*)(X + (size_t)s * NQKV + co);
  float e0[3], e1[3];
  float ss = 0.f;
  #pragma unroll
  for (int i = 0; i < 3; ++i) {
    unsigned int u = row[tid + i * 256];
    float a = __uint_as_float(u << 16);
    float b = __uint_as_float(u & 0xffff0000u);
    e0[i] = a; e1[i] = b;
    ss += a * a + b * b;
  }
  #pragma unroll
  for (int off = 32; off > 0; off >>= 1) ss += __shfl_down(ss, off, 64);
  __shared__ float wsum[4];
  if ((tid & 63) == 0) wsum[tid >> 6] = ss;
  __syncthreads();
  float rs = rsqrtf((wsum[0] + wsum[1] + wsum[2] + wsum[3]) * (1.f / DMODEL) + 1e-5f);
  const int p = fwdperm(s);
  #pragma unroll
  for (int i = 0; i < 3; ++i) {
    int pi = tid + i * 256;             // pair index 0..767
    int n = pi >> 6, d2 = pi & 63;
    float c  = freqs[(size_t)s * 128 + 2 * d2];
    float sn = freqs[(size_t)s * 128 + 2 * d2 + 1];
    float y0 = e0[i] * rs * g[2 * pi];
    float y1 = e1[i] * rs * g[2 * pi + 1];
    float o0 = y0 * c - y1 * sn;
    float o1 = y0 * sn + y1 * c;
    __hip_bfloat16 b0 = __float2bfloat16(o0), b1 = __float2bfloat16(o1);
    unsigned int u = ((unsigned int)(*(unsigned short*)&b1) << 16) | (*(unsigned short*)&b0);
    ((unsigned int*)Out)[(((size_t)n * S_LEN + p) * HDIM + 2 * d2) >> 1] = u;
  }
}

// ---------------------------------------------------------------------------
__global__ __launch_bounds__(256) void v_transpose(
    const __hip_bfloat16* __restrict__ Vsec, __hip_bfloat16* __restrict__ Vt)
{
  __shared__ __hip_bfloat16 Ls[64][136];
  const int p0 = blockIdx.x * 64, h = blockIdx.y, t = threadIdx.x;
  {
    int pl = t & 63, dg = t >> 6;
    int sidx = invperm(p0 + pl);
    const uint4* src = (const uint4*)(Vsec + (size_t)sidx * NQKV + h * HDIM + dg * 32);
    #pragma unroll
    for (int i = 0; i < 4; ++i) {
      uint4 v = src[i];
      *(uint4*)&Ls[pl][dg * 32 + i * 8] = v;
    }
  }
  __syncthreads();
  {
    int d = t >> 1, ph = t & 1;
    unsigned short tmp[32];
    #pragma unroll
    for (int i = 0; i < 32; ++i) tmp[i] = *(unsigned short*)&Ls[ph * 32 + i][d];
    uint4* dst = (uint4*)(Vt + ((size_t)h * HDIM + d) * S_LEN + p0 + ph * 32);
    #pragma unroll
    for (int i = 0; i < 4; ++i) dst[i] = ((uint4*)tmp)[i];
  }
}

// ---------------------------------------------------------------------------
// MFMA flash attention, double-buffered K/V with early prefetch.
// grid=(48 qtile, 12 head), 4 waves x 16 q-rows, KC=64 chunks.
// Heavy blocks (tg2: 48 chunks) mapped to low blockIdx for launch-order tail.
// ---------------------------------------------------------------------------
__global__ __launch_bounds__(256) void attn_mfma(
    const __hip_bfloat16* __restrict__ Qp, const __hip_bfloat16* __restrict__ Kp,
    const __hip_bfloat16* __restrict__ Vt, __hip_bfloat16* __restrict__ AO)
{
  __shared__ __hip_bfloat16 Ks[2][64 * 128];       // [key][d], swizzled
  __shared__ __hip_bfloat16 Vs[2][64 * 128];       // [d][key], swizzled
  __shared__ __align__(16) __hip_bfloat16 Pl[4][16][72];  // 64 keys + 8 pad

  const int bx = blockIdx.x, h = blockIdx.y;
  // heavy-first: bx 0..23 -> qt 24..47 (tg2,tg3), 24..35 -> tg1, 36..47 -> tg0
  const int qt = (bx < 24) ? bx + 24 : (bx < 36) ? bx - 12 : bx - 36;
  const int tid = threadIdx.x, lane = tid & 63, wid = tid >> 6;
  const int l15 = lane & 15, l4 = lane >> 4;
  const float SC2 = 0.08838834764831843f * 1.4426950408889634f;

  const char* Kh = (const char*)(Kp + (size_t)h * S_LEN * HDIM);
  const char* Vh = (const char*)(Vt + (size_t)h * HDIM * S_LEN);

  const int tg = qt / 12;
  const int NC = (tg == 0) ? 24 : (tg == 2) ? 48 : 36;

  auto k0_of = [&](int ci) { return ci * 64 + ((tg == 3 && ci >= 12) ? 768 : 0); };

  auto STAGE = [&](int buf, int k0) {
    #pragma unroll
    for (int i = 0; i < 4; ++i) {
      int slot = i * 256 + tid;
      int krow = slot >> 4;
      int kb = (slot & 15) * 16;
      int ksb = kb ^ ((krow & 7) << 4);
      gload_lds16(Kh + ((size_t)(k0 + krow) * HDIM) * 2 + ksb,
                  (char*)Ks[buf] + ((size_t)i * 256 + wid * 64) * 16);
      int vrow = slot >> 3;
      int vb = (slot & 7) * 16;
      int vsb = vb ^ ((vrow & 7) << 4);
      gload_lds16(Vh + ((size_t)vrow * S_LEN + k0) * 2 + vsb,
                  (char*)Vs[buf] + ((size_t)i * 256 + wid * 64) * 16);
    }
  };

  // hoist Q fragments (A-operand) to registers
  bf16x8 aq[4];
  {
    const __hip_bfloat16* qr =
        Qp + (size_t)h * S_LEN * HDIM + (size_t)(qt * 64 + wid * 16 + l15) * HDIM + l4 * 8;
    #pragma unroll
    for (int dc = 0; dc < 4; ++dc) aq[dc] = *(const bf16x8*)(qr + dc * 32);
  }

  f32x4 oacc[8] = {};
  float m2[4] = {-1e30f, -1e30f, -1e30f, -1e30f};
  float lsum[4] = {};   // per-lane partial (own 4 columns); reduced in epilogue

  STAGE(0, k0_of(0));
  __syncthreads();
  int cur = 0;

  for (int ci = 0; ci < NC; ++ci) {
    if (ci + 1 < NC) STAGE(cur ^ 1, k0_of(ci + 1));

    // QK^T: S[16q][64k] per wave
    f32x4 sfr[4] = {};
    #pragma unroll
    for (int ct = 0; ct < 4; ++ct) {
      int key = ct * 16 + l15;
      #pragma unroll
      for (int dc = 0; dc < 4; ++dc) {
        int b = (dc * 64 + l4 * 16) ^ ((key & 7) << 4);
        bf16x8 bk = *(const bf16x8*)((const char*)Ks[cur] + key * 256 + b);
        sfr[ct] = __builtin_amdgcn_mfma_f32_16x16x32_bf16(aq[dc], bk, sfr[ct], 0, 0, 0);
      }
    }
    // online softmax (rows at l4*4+r; reduce over low-4 lane bits)
    float mxr[4];
    bool grow = false;
    #pragma unroll
    for (int r = 0; r < 4; ++r) {
      float mx = fmaxf(fmaxf(sfr[0][r], sfr[1][r]), fmaxf(sfr[2][r], sfr[3][r])) * SC2;
      #pragma unroll
      for (int o = 1; o < 16; o <<= 1) mx = fmaxf(mx, __shfl_xor(mx, o, 64));
      mxr[r] = mx;
      if (mx > m2[r]) grow = true;
    }
    if (__any(grow)) {
      float corr[4];
      #pragma unroll
      for (int r = 0; r < 4; ++r) {
        float mn = fmaxf(m2[r], mxr[r]);
        corr[r] = exp2f(m2[r] - mn);
        m2[r] = mn;
        lsum[r] *= corr[r];
      }
      #pragma unroll
      for (int n = 0; n < 8; ++n)
        #pragma unroll
        for (int r = 0; r < 4; ++r) oacc[n][r] *= corr[r];
    }
    float pr[4][4];
    #pragma unroll
    for (int ct = 0; ct < 4; ++ct)
      #pragma unroll
      for (int r = 0; r < 4; ++r) {
        float p = exp2f(sfr[ct][r] * SC2 - m2[r]);
        pr[ct][r] = p;
        lsum[r] += p;
      }
    // P -> per-wave LDS tile (A-operand relayout)
    #pragma unroll
    for (int ct = 0; ct < 4; ++ct)
      #pragma unroll
      for (int r = 0; r < 4; ++r)
        Pl[wid][l4 * 4 + r][ct * 16 + l15] = __float2bfloat16(pr[ct][r]);
    asm volatile("s_waitcnt lgkmcnt(0)" ::: "memory");
    __builtin_amdgcn_sched_barrier(0);
    // PV
    #pragma unroll
    for (int ks = 0; ks < 2; ++ks) {
      bf16x8 pa = *(const bf16x8*)&Pl[wid][l15][ks * 32 + l4 * 8];
      #pragma unroll
      for (int n = 0; n < 8; ++n) {
        int d = n * 16 + l15;
        int b = (ks * 64 + l4 * 16) ^ ((d & 7) << 4);
        bf16x8 bv = *(const bf16x8*)((const char*)Vs[cur] + d * 128 + b);
        oacc[n] = __builtin_amdgcn_mfma_f32_16x16x32_bf16(pa, bv, oacc[n], 0, 0, 0);
      }
    }
    __syncthreads();   // drains prefetch vmcnt + releases cur buffer
    cur ^= 1;
  }

  // epilogue: reduce lsum across the 16-lane group, normalize, scatter
  #pragma unroll
  for (int r = 0; r < 4; ++r) {
    float t = lsum[r];
    #pragma unroll
    for (int o = 1; o < 16; o <<= 1) t += __shfl_xor(t, o, 64);
    lsum[r] = t;
  }
  #pragma unroll
  for (int r = 0; r < 4; ++r) {
    int qglob = qt * 64 + wid * 16 + l4 * 4 + r;
    int sorig = invperm(qglob);
    float inv = 1.0f / lsum[r];
    __hip_bfloat16* dst = AO + (size_t)sorig * DMODEL + h * HDIM;
    #pragma unroll
    for (int n = 0; n < 8; ++n)
      dst[n * 16 + l15] = __float2bfloat16(oacc[n][r] * inv);
  }
}

// ---------------------------------------------------------------------------
extern "C" void kernel_launch(void* const* d_in, const int* in_sizes, int n_in,
                              void* d_out, int out_size, void* d_ws, size_t ws_size,
                              hipStream_t stream)
{
  (void)in_sizes; (void)n_in; (void)out_size; (void)ws_size;
  const float* x     = (const float*)d_in[0];
  const float* freqs = (const float*)d_in[1];
  const float* Wq    = (const float*)d_in[2];
  const float* bq    = (const float*)d_in[3];
  const float* Wk    = (const float*)d_in[4];
  const float* bk    = (const float*)d_in[5];
  const float* Wv    = (const float*)d_in[6];
  const float* bv    = (const float*)d_in[7];
  const float* Wo    = (const float*)d_in[8];
  const float* bo    = (const float*)d_in[9];
  const float* gq    = (const float*)d_in[10];
  const float* gk    = (const float*)d_in[11];
  float* out = (float*)d_out;

  char* w = (char*)d_ws;
  __hip_bfloat16* xbf    = (__hip_bfloat16*)(w);               // 9,437,184 B
  __hip_bfloat16* Wtqkv  = (__hip_bfloat16*)(w + 9437184);     // 14,155,776
  __hip_bfloat16* Wot    = (__hip_bfloat16*)(w + 23592960);    // 4,718,592
  __hip_bfloat16* QKVbf  = (__hip_bfloat16*)(w + 28311552);    // 28,311,552
  __hip_bfloat16* Qp     = (__hip_bfloat16*)(w + 56623104);    // 9,437,184
  __hip_bfloat16* Kp     = (__hip_bfloat16*)(w + 66060288);    // 9,437,184
  __hip_bfloat16* Vtb    = (__hip_bfloat16*)(w + 75497472);    // 9,437,184
  __hip_bfloat16* AO     = (__hip_bfloat16*)(w + 84934656);    // 9,437,184
  float*          bqkv   = (float*)(w + 94371840);             // 18,432

  // prep: converts / transposes / bias concat
  hipLaunchKernelGGL(convert_f32_bf16, dim3(4608), dim3(256), 0, stream,
                     x, xbf, (S_LEN * DMODEL) / 4);
  dim3 tg(24, 24);
  hipLaunchKernelGGL(transpose_convert, tg, dim3(256), 0, stream, Wq, Wtqkv);
  hipLaunchKernelGGL(transpose_convert, tg, dim3(256), 0, stream, Wk, Wtqkv + (size_t)1536 * 1536);
  hipLaunchKernelGGL(transpose_convert, tg, dim3(256), 0, stream, Wv, Wtqkv + (size_t)3072 * 1536);
  hipLaunchKernelGGL(transpose_convert, tg, dim3(256), 0, stream, Wo, Wot);
  hipLaunchKernelGGL(concat3, dim3(18), dim3(256), 0, stream, bq, bk, bv, bqkv);

  // fused QKV GEMM: [3072,1536] @ [1536,4608] -> bf16
  hipLaunchKernelGGL((gemm_bt<__hip_bfloat16>), dim3(NQKV / 128, S_LEN / 128), dim3(256), 0,
                     stream, xbf, Wtqkv, bqkv, QKVbf, S_LEN, NQKV, DMODEL);

  // norm+rope -> permuted head-blocked Q/K ; V -> transposed+permuted
  hipLaunchKernelGGL(norm_rope_perm, dim3(S_LEN), dim3(256), 0, stream, QKVbf, 0, gq, freqs, Qp);
  hipLaunchKernelGGL(norm_rope_perm, dim3(S_LEN), dim3(256), 0, stream, QKVbf, 1536, gk, freqs, Kp);
  hipLaunchKernelGGL(v_transpose, dim3(48, 12), dim3(256), 0, stream, QKVbf + 3072, Vtb);

  // attention
  hipLaunchKernelGGL(attn_mfma, dim3(48, NHEAD), dim3(256), 0, stream, Qp, Kp, Vtb, AO);

  // output projection
  hipLaunchKernelGGL((gemm_bt<float>), dim3(DMODEL / 128, S_LEN / 128), dim3(256), 0,
                     stream, AO, Wot, bo, out, S_LEN, DMODEL, DMODEL);
}